// Round 4
// baseline (186.594 us; speedup 1.0000x reference)
//
#include <hip/hip_runtime.h>
#include <math.h>

// [B=2, 1, D=192, H=192, W=192] fp32
#define W 192
#define H 192
#define DEPTH 192
#define BATCH 2
#define TW 64          // tile width
#define TH 8           // tile height
#define DC 12          // output planes per block -> grid 72*16*2 = 2304 blocks
#define HW (H * W)
#define VOL ((size_t)DEPTH * HW)
#define NPAIR 7        // plane pairs d0-1 .. d0+12
#define LROW 128       // floats per LDS row: 64 cols * (sh,dh)
#define LPL (10 * LROW)
#define NUNIT 640      // staging units per pair: 2 arrays * 2 planes * 10 rows * 16 col4-groups

// Separable Sobel, horizontal combine done at STAGING time:
//   staging writes (sh, dh) = (x[w-1]+2x[w]+x[w+1], x[w+1]-x[w-1]) interleaved to LDS.
// Compute reads (sh,dh) for rows r-1..r+1 as one b128 per row per array (lane stride 16B,
// conflict-free) and does only the vertical + D combines:
//   adx = dh(r-1)+2dh(r)+dh(r+1); asx = sh(r-1)+2sh(r)+sh(r+1); ady = sh(r-1)-sh(r+1)
//   gx = s_d(adx), gy = s_d(ady), gz = d_d(asx) via 3-deep D-rolling history.
// mse centers (pred,gt) + mask prefetched from global as float2 (L1-hot).

__global__ __launch_bounds__(256) void sobel_loss_part(
    const float* __restrict__ pred, const float* __restrict__ gt,
    const float* __restrict__ mask, float* __restrict__ partials)
{
    __shared__ __align__(16) float lds[4 * LPL];   // (a*2+q) regions, 20.5 KB

    const int tid = threadIdx.x;
    const int tx = blockIdx.x % 3, ty = blockIdx.x / 3;
    const int w0 = tx * TW, h0 = ty * TH;
    const int d0 = blockIdx.y * DC;
    const size_t base = (size_t)blockIdx.z * VOL;

    // compute mapping: thread = 1 row (wy) x 2 adjacent cols (wxo, wxo+1)
    const int wy  = tid >> 5;
    const int wxo = (tid & 31) << 1;
    const size_t coff = base + (size_t)(h0 + wy) * W + (w0 + wxo);

    // ---- staging unit geometry (loop-invariant): u = tid + 256k ----
    // a = u/320, q = (u%320)/160, r = (u%160)>>4, cg = u&15
    int u_st[3], u_rowok[3], u_lok[3], u_rok[3], u_q[3], u_lds[3];
    size_t u_goff[3];
    const float* u_src[3];
    #pragma unroll
    for (int k = 0; k < 3; ++k) {
        int u = tid + 256 * k;
        int uu = (u < NUNIT) ? u : 0;
        int a = uu / 320; int rem = uu - a * 320;
        int q = rem / 160; int rem2 = rem - q * 160;
        int r = rem2 >> 4; int cg = rem2 & 15;
        int y = h0 - 1 + r;
        int x = w0 + 4 * cg;
        u_st[k]    = (u < NUNIT);
        u_rowok[k] = u_st[k] && ((unsigned)y < (unsigned)H);
        u_lok[k]   = (x > 0);
        u_rok[k]   = (x + 4 < W);
        u_goff[k]  = u_rowok[k] ? ((size_t)y * W + x) : 0;
        u_q[k]     = q;
        u_lds[k]   = ((a * 2 + q) * 10 + r) * LROW + cg * 8;
        u_src[k]   = a ? gt : pred;
    }

    float4 X[3]; float XL[3], XR[3];
    auto load_pair = [&](int s) {
        const int p0 = d0 - 1 + 2 * s;
        #pragma unroll
        for (int k = 0; k < 3; ++k) {
            const int p = p0 + u_q[k];
            const bool ok = u_rowok[k] && (p >= 0) && (p < DEPTH);
            const float* sp = u_src[k] + base + (size_t)p * HW + u_goff[k];
            X[k]  = ok ? *(const float4*)sp : make_float4(0.f, 0.f, 0.f, 0.f);
            XL[k] = (ok && u_lok[k]) ? sp[-1] : 0.f;
            XR[k] = (ok && u_rok[k]) ? sp[4]  : 0.f;
        }
    };

    float2 Mn = {0,0}, Mn1 = {0,0}, Pn = {0,0}, Pn1 = {0,0}, Gn = {0,0}, Gn1 = {0,0};
    auto load_ctr = [&](int s) {   // centers/mask for round-s outputs: planes d0+2s-2, d0+2s-1
        size_t o0 = coff + (size_t)(d0 + 2 * s - 2) * HW;
        size_t o1 = coff + (size_t)(d0 + 2 * s - 1) * HW;
        Mn  = *(const float2*)(mask + o0);  Mn1 = *(const float2*)(mask + o1);
        Pn  = *(const float2*)(pred + o0);  Pn1 = *(const float2*)(pred + o1);
        Gn  = *(const float2*)(gt   + o0);  Gn1 = *(const float2*)(gt   + o1);
    };

    // 3-deep D-rolling history [array][col][slot]; slots rotate by compile-time t%3
    float hdx[2][2][3], hsx[2][2][3], hdy[2][2][3];
    #pragma unroll
    for (int a = 0; a < 2; ++a)
        #pragma unroll
        for (int o = 0; o < 2; ++o)
            #pragma unroll
            for (int j = 0; j < 3; ++j) { hdx[a][o][j] = 0.f; hsx[a][o][j] = 0.f; hdy[a][o][j] = 0.f; }
    float acc = 0.f;

    load_pair(0);

    #pragma unroll
    for (int s = 0; s < NPAIR; ++s) {
        __syncthreads();                 // previous round's LDS reads complete
        #pragma unroll
        for (int k = 0; k < 3; ++k) {
            if (u_st[k]) {
                float4 x4 = X[k]; float xl = XL[k], xr = XR[k];
                float4 w1, w2;
                w1.x = xl   + 2.f * x4.x + x4.y;  w1.y = x4.y - xl;
                w1.z = x4.x + 2.f * x4.y + x4.z;  w1.w = x4.z - x4.x;
                w2.x = x4.y + 2.f * x4.z + x4.w;  w2.y = x4.w - x4.y;
                w2.z = x4.z + 2.f * x4.w + xr;    w2.w = xr   - x4.z;
                *(float4*)(lds + u_lds[k])     = w1;
                *(float4*)(lds + u_lds[k] + 4) = w2;
            }
        }
        __syncthreads();

        float2 Mc0 = Mn, Mc1 = Mn1, Pc0 = Pn, Pc1 = Pn1, Gc0 = Gn, Gc1 = Gn1;
        if (s + 1 < NPAIR) { load_pair(s + 1); load_ctr(s + 1); }

        #pragma unroll
        for (int q = 0; q < 2; ++q) {
            const int t = 2 * s + q;            // compile-time under full unroll
            const int wsl = t % 3;              // slot for plane t-1 (newest)
            const int i0  = (t + 1) % 3;        // plane od-1
            const int i1  = (t + 2) % 3;        // plane od
            const int i2  = wsl;                // plane od+1

            const float* LA = lds + (q * 10 + wy) * LROW + wxo * 2;        // a=0
            const float* LB = lds + ((2 + q) * 10 + wy) * LROW + wxo * 2;  // a=1
            float4 A0 = *(const float4*)(LA);
            float4 A1 = *(const float4*)(LA + LROW);
            float4 A2 = *(const float4*)(LA + 2 * LROW);
            float4 B0 = *(const float4*)(LB);
            float4 B1 = *(const float4*)(LB + LROW);
            float4 B2 = *(const float4*)(LB + 2 * LROW);

            #pragma unroll
            for (int o = 0; o < 2; ++o) {
                float sA0 = o ? A0.z : A0.x, dA0 = o ? A0.w : A0.y;
                float sA1 = o ? A1.z : A1.x, dA1 = o ? A1.w : A1.y;
                float sA2 = o ? A2.z : A2.x, dA2 = o ? A2.w : A2.y;
                hdx[0][o][wsl] = dA0 + 2.f * dA1 + dA2;
                hsx[0][o][wsl] = sA0 + 2.f * sA1 + sA2;
                hdy[0][o][wsl] = sA0 - sA2;
                float sB0 = o ? B0.z : B0.x, dB0 = o ? B0.w : B0.y;
                float sB1 = o ? B1.z : B1.x, dB1 = o ? B1.w : B1.y;
                float sB2 = o ? B2.z : B2.x, dB2 = o ? B2.w : B2.y;
                hdx[1][o][wsl] = dB0 + 2.f * dB1 + dB2;
                hsx[1][o][wsl] = sB0 + 2.f * sB1 + sB2;
                hdy[1][o][wsl] = sB0 - sB2;
            }

            if (t >= 2) {
                const float2 M = q ? Mc1 : Mc0;
                const float2 P = q ? Pc1 : Pc0;
                const float2 G = q ? Gc1 : Gc0;
                #pragma unroll
                for (int o = 0; o < 2; ++o) {
                    float gx = hdx[0][o][i0] + 2.f * hdx[0][o][i1] + hdx[0][o][i2];
                    float gy = hdy[0][o][i0] + 2.f * hdy[0][o][i1] + hdy[0][o][i2];
                    float gz = hsx[0][o][i0] - hsx[0][o][i2];
                    float ga = __builtin_amdgcn_sqrtf(
                        fmaf(gz, gz, fmaf(gy, gy, fmaf(gx, gx, 1e-10f))));
                    float hx = hdx[1][o][i0] + 2.f * hdx[1][o][i1] + hdx[1][o][i2];
                    float hy = hdy[1][o][i0] + 2.f * hdy[1][o][i1] + hdy[1][o][i2];
                    float hz = hsx[1][o][i0] - hsx[1][o][i2];
                    float gb = __builtin_amdgcn_sqrtf(
                        fmaf(hz, hz, fmaf(hy, hy, fmaf(hx, hx, 1e-10f))));
                    float m  = o ? M.y : M.x;
                    float dm = (o ? P.y : P.x) - (o ? G.y : G.x);
                    float mse = dm * dm * m;
                    float dg  = gb - ga;
                    float mge = dg * dg * m;
                    // tanh(x) = 1 - 2/(e^{2x}+1), x>=0; 1+tanh = 2 - 2*rcp(e^{2x}+1)
                    float ex = __expf(mge + mge);
                    float rc = __builtin_amdgcn_rcpf(ex + 1.f);
                    float c  = fmaf(-2.f, rc, 2.f);
                    acc = fmaf(mse, c, acc);
                }
            }
        }
    }

    // block reduction
    float v = acc;
    #pragma unroll
    for (int o = 32; o > 0; o >>= 1) v += __shfl_down(v, o, 64);
    __shared__ float red[4];
    if ((tid & 63) == 0) red[tid >> 6] = v;
    __syncthreads();
    if (tid == 0) {
        partials[(size_t)blockIdx.z * (gridDim.x * gridDim.y)
                 + (size_t)blockIdx.y * gridDim.x + blockIdx.x]
            = red[0] + red[1] + red[2] + red[3];
    }
}

__global__ __launch_bounds__(256) void reduce_final(
    const float* __restrict__ partials, int n, float* __restrict__ out)
{
    int tid = threadIdx.x;
    double s = 0.0;
    for (int i = tid; i < n; i += 256) s += (double)partials[i];
    #pragma unroll
    for (int o = 32; o > 0; o >>= 1) s += __shfl_down(s, o, 64);
    __shared__ double red[4];
    if ((tid & 63) == 0) red[tid >> 6] = s;
    __syncthreads();
    if (tid == 0) {
        double t = red[0] + red[1] + red[2] + red[3];
        const double ntot = (double)BATCH * (double)DEPTH * (double)H * (double)W;
        out[0] = (float)(t / ntot);
    }
}

extern "C" void kernel_launch(void* const* d_in, const int* in_sizes, int n_in,
                              void* d_out, int out_size, void* d_ws, size_t ws_size,
                              hipStream_t stream) {
    const float* pred = (const float*)d_in[0];
    const float* gt   = (const float*)d_in[1];
    const float* mask = (const float*)d_in[2];
    float* partials = (float*)d_ws;

    dim3 grid((W / TW) * (H / TH), DEPTH / DC, BATCH);   // 72 x 16 x 2 = 2304
    sobel_loss_part<<<grid, 256, 0, stream>>>(pred, gt, mask, partials);

    int nparts = grid.x * grid.y * grid.z;
    reduce_final<<<1, 256, 0, stream>>>(partials, nparts, (float*)d_out);
}